// Round 1
// baseline (4199.445 us; speedup 1.0000x reference)
//
#include <hip/hip_runtime.h>
#include <math.h>

#define SS 4096
#define DE 256
#define DM 64
#define DC 64
#define DIN 320
#define DEPTH 4
#define DTс 0.1f
#define KSPLIT 2
#define BQ 16
#define BK 16

// ---------------- output offsets (floats) ----------------
#define OFF_E     (SS*DE)                 // 1048576
#define OFF_P     (OFF_E + SS)
#define OFF_G     (OFF_P + SS)
#define OFF_M     (OFF_G + SS)            // 1060864
#define OFF_C     (OFF_M + SS*DM)         // 1323008
#define OFF_L     (OFF_C + SS*DM)         // 1585152
#define OFF_ALIVE (OFF_L + SS)            // 1589248
#define OFF_DIED  (OFF_ALIVE + SS)        // 1593344

// ---------------- ws offsets (floats) ----------------
#define WS_E     0
#define WS_Q     (SS*DE)
#define WS_K     (2*SS*DE)
#define WS_V     (3*SS*DE)
#define WS_M     (4*SS*DE)                // + SS*DM
#define WS_EE    (WS_M + SS*DM)
#define WS_PP    (WS_EE + SS)
#define WS_GG    (WS_PP + SS)
#define WS_LL    (WS_GG + SS)
#define WS_SIN   (WS_LL + SS)
#define WS_PM    (WS_SIN + SS)            // KSPLIT*SS
#define WS_PL    (WS_PM + KSPLIT*SS)
#define WS_PO    (WS_PL + KSPLIT*SS)      // KSPLIT*SS*DE

// ================= projections: q/k/v = [e|c] @ W + b =================
__global__ __launch_bounds__(256) void proj_kernel(
    const float* __restrict__ e_ws, const float* __restrict__ c,
    const float* __restrict__ wq, const float* __restrict__ wk, const float* __restrict__ wv,
    const float* __restrict__ bq, const float* __restrict__ bk, const float* __restrict__ bv,
    float* __restrict__ qo, float* __restrict__ ko, float* __restrict__ vo, int layer)
{
    const int rt = blockIdx.x;   // 64 row tiles of 64
    const int nt = blockIdx.y;   // 4 col tiles of 64
    const int z  = blockIdx.z;   // 0=q 1=k 2=v
    const float* W = (z==0 ? wq : (z==1 ? wk : wv)) + (size_t)layer*DIN*DE;
    const float* B = (z==0 ? bq : (z==1 ? bk : bv)) + (size_t)layer*DE;
    float* O = (z==0 ? qo : (z==1 ? ko : vo));

    __shared__ float xs[16][68];  // [k][row] transposed, padded
    __shared__ float wsh[16][64]; // [k][n]

    const int tid = threadIdx.x;
    const int tr = tid >> 4, tc = tid & 15;
    const int row0 = rt*64, col0 = nt*64;
    float acc[4][4] = {};

    for (int kk0 = 0; kk0 < DIN; kk0 += 16) {
        {   // x tile: 64 rows x 16 k
            int r  = tid >> 2;
            int q4 = tid & 3;
            int kd = kk0 + q4*4;
            float4 xv;
            if (kd < DE) xv = *(const float4*)&e_ws[(size_t)(row0+r)*DE + kd];
            else         xv = *(const float4*)&c[(size_t)(row0+r)*DC + (kd-DE)];
            xs[q4*4+0][r] = xv.x; xs[q4*4+1][r] = xv.y;
            xs[q4*4+2][r] = xv.z; xs[q4*4+3][r] = xv.w;
        }
        {   // W tile: 16 k x 64 n
            int kl = tid >> 4, n4 = tid & 15;
            *(float4*)&wsh[kl][n4*4] = *(const float4*)&W[(size_t)(kk0+kl)*DE + col0 + n4*4];
        }
        __syncthreads();
        #pragma unroll
        for (int k = 0; k < 16; ++k) {
            float4 a = *(float4*)&xs[k][tr*4];
            float4 b = *(float4*)&wsh[k][tc*4];
            acc[0][0] += a.x*b.x; acc[0][1] += a.x*b.y; acc[0][2] += a.x*b.z; acc[0][3] += a.x*b.w;
            acc[1][0] += a.y*b.x; acc[1][1] += a.y*b.y; acc[1][2] += a.y*b.z; acc[1][3] += a.y*b.w;
            acc[2][0] += a.z*b.x; acc[2][1] += a.z*b.y; acc[2][2] += a.z*b.z; acc[2][3] += a.z*b.w;
            acc[3][0] += a.w*b.x; acc[3][1] += a.w*b.y; acc[3][2] += a.w*b.z; acc[3][3] += a.w*b.w;
        }
        __syncthreads();
    }
    float4 bias = *(const float4*)&B[col0 + tc*4];
    #pragma unroll
    for (int i = 0; i < 4; ++i) {
        int row = row0 + tr*4 + i;
        float4 o4 = make_float4(acc[i][0]+bias.x, acc[i][1]+bias.y, acc[i][2]+bias.z, acc[i][3]+bias.w);
        *(float4*)&O[(size_t)row*DE + col0 + tc*4] = o4;
    }
}

// ================= flash attention with multiplicative mask =================
__global__ __launch_bounds__(256) void attn_kernel(
    const float* __restrict__ qg, const float* __restrict__ kg, const float* __restrict__ vg,
    const float* __restrict__ m_ws, const float* __restrict__ l_ws,
    float* __restrict__ part_o, float* __restrict__ part_m, float* __restrict__ part_l)
{
    __shared__ float kt[BK*DE];
    __shared__ float vt[BK*DE];
    __shared__ float mt[BK*DM];
    __shared__ float lt[BK];

    const int tid = threadIdx.x;
    const int r = tid >> 4;         // 0..15 query row in tile
    const int g = tid & 15;         // 0..15 col group
    const int qt = blockIdx.x;
    const int split = blockIdx.y;
    const int row = qt*BQ + r;

    float4 qreg[4];
    #pragma unroll
    for (int ch = 0; ch < 4; ++ch)
        qreg[ch] = *(const float4*)&qg[(size_t)row*DE + ch*64 + g*4];
    float4 mq = *(const float4*)&m_ws[(size_t)row*DM + g*4];
    const float lsca = l_ws[row];

    float mx = -__builtin_inff();
    float lsum = 0.f;
    float4 o[4] = {make_float4(0,0,0,0),make_float4(0,0,0,0),make_float4(0,0,0,0),make_float4(0,0,0,0)};

    const int t_begin = split*(SS/KSPLIT);
    const int t_end   = t_begin + (SS/KSPLIT);
    for (int t0 = t_begin; t0 < t_end; t0 += BK) {
        __syncthreads();
        for (int idx = tid; idx < BK*DE/4; idx += 256) {
            int tl = idx >> 6, d4 = idx & 63;
            *(float4*)&kt[tl*DE + d4*4] = *(const float4*)&kg[(size_t)(t0+tl)*DE + d4*4];
            *(float4*)&vt[tl*DE + d4*4] = *(const float4*)&vg[(size_t)(t0+tl)*DE + d4*4];
        }
        {
            int tl = tid >> 4, d4 = tid & 15;
            *(float4*)&mt[tl*DM + d4*4] = *(const float4*)&m_ws[(size_t)(t0+tl)*DM + d4*4];
        }
        if (tid < BK) lt[tid] = l_ws[t0 + tid];
        __syncthreads();

        #pragma unroll 4
        for (int tl = 0; tl < BK; ++tl) {
            float sqk = 0.f, smm = 0.f;
            #pragma unroll
            for (int ch = 0; ch < 4; ++ch) {
                float4 kk = *(float4*)&kt[tl*DE + ch*64 + g*4];
                sqk += qreg[ch].x*kk.x + qreg[ch].y*kk.y + qreg[ch].z*kk.z + qreg[ch].w*kk.w;
            }
            {
                float4 mk = *(float4*)&mt[tl*DM + g*4];
                smm += mq.x*mk.x + mq.y*mk.y + mq.z*mk.z + mq.w*mk.w;
            }
            #pragma unroll
            for (int mask = 1; mask <= 8; mask <<= 1) {
                sqk += __shfl_xor(sqk, mask, 64);
                smm += __shfl_xor(smm, mask, 64);
            }
            float score = sqk * 0.0625f * smm * (lsca * lt[tl]);
            float nm = fmaxf(mx, score);
            float p = __expf(score - nm);
            if (nm > mx) {
                float alpha = __expf(mx - nm);
                lsum *= alpha;
                #pragma unroll
                for (int ch = 0; ch < 4; ++ch) {
                    o[ch].x *= alpha; o[ch].y *= alpha; o[ch].z *= alpha; o[ch].w *= alpha;
                }
                mx = nm;
            }
            lsum += p;
            #pragma unroll
            for (int ch = 0; ch < 4; ++ch) {
                float4 vv = *(float4*)&vt[tl*DE + ch*64 + g*4];
                o[ch].x += p*vv.x; o[ch].y += p*vv.y; o[ch].z += p*vv.z; o[ch].w += p*vv.w;
            }
        }
    }
    #pragma unroll
    for (int ch = 0; ch < 4; ++ch)
        *(float4*)&part_o[((size_t)split*SS + row)*DE + ch*64 + g*4] = o[ch];
    if (g == 0) {
        part_m[split*SS + row] = mx;
        part_l[split*SS + row] = lsum;
    }
}

// ================= combine splits, e += h, S_in = ||h||^2 =================
__global__ __launch_bounds__(256) void combine_kernel(
    const float* __restrict__ part_o, const float* __restrict__ part_m, const float* __restrict__ part_l,
    float* __restrict__ e_ws, float* __restrict__ S_in)
{
    const int w = threadIdx.x >> 6;
    const int lane = threadIdx.x & 63;
    const int row = blockIdx.x*4 + w;

    float M = -__builtin_inff();
    #pragma unroll
    for (int s = 0; s < KSPLIT; ++s) M = fmaxf(M, part_m[s*SS + row]);
    float L = 0.f;
    float wsc[KSPLIT];
    #pragma unroll
    for (int s = 0; s < KSPLIT; ++s) {
        wsc[s] = __expf(part_m[s*SS + row] - M);
        L += part_l[s*SS + row] * wsc[s];
    }
    const float invL = 1.f / L;
    float4 od = make_float4(0,0,0,0);
    #pragma unroll
    for (int s = 0; s < KSPLIT; ++s) {
        float4 po = *(const float4*)&part_o[((size_t)s*SS + row)*DE + lane*4];
        float f = wsc[s] * invL;
        od.x += po.x*f; od.y += po.y*f; od.z += po.z*f; od.w += po.w*f;
    }
    float4 ev = *(float4*)&e_ws[(size_t)row*DE + lane*4];
    ev.x += od.x; ev.y += od.y; ev.z += od.z; ev.w += od.w;
    *(float4*)&e_ws[(size_t)row*DE + lane*4] = ev;

    float ssq = od.x*od.x + od.y*od.y + od.z*od.z + od.w*od.w;
    #pragma unroll
    for (int mask = 1; mask < 64; mask <<= 1) ssq += __shfl_xor(ssq, mask, 64);
    if (lane == 0) S_in[row] = ssq;
}

// ================= thermodynamic ODE =================
__global__ __launch_bounds__(256) void ode_kernel(
    const float* __restrict__ S_in,
    float* __restrict__ E_ws, float* __restrict__ P_ws, float* __restrict__ G_ws,
    float* __restrict__ m_ws, float* __restrict__ l_ws,
    const float* __restrict__ alpha, const float* __restrict__ beta,
    const float* __restrict__ gamma_, const float* __restrict__ basal, int layer)
{
    const int w = threadIdx.x >> 6;
    const int lane = threadIdx.x & 63;
    const int row = blockIdx.x*4 + w;

    const float a = alpha[layer], b = beta[layer], gm = gamma_[layer], bas = basal[layer];
    const float E = E_ws[row], P = P_ws[row];
    const float Sin = S_in[row];
    const float PE = P*E;
    const float Pn = fmaxf(0.f, P + (a*Sin - b*PE)*DTс);
    const float En = fmaxf(0.f, E + (bas - gm*PE)*DTс);
    const float mtg = 1.f / (1.f + __expf(-(En - Pn)));

    float mv = m_ws[(size_t)row*DM + lane];
    m_ws[(size_t)row*DM + lane] = 0.9f*mv + 0.1f*mtg;

    if (lane == 0) {
        E_ws[row] = En;
        P_ws[row] = Pn;
        G_ws[row] = G_ws[row] + (0.1f*En - 0.5f*Pn)*DTс;
        float ldec = 0.01f + 0.5f*fmaxf(0.f, Pn - 2.0f);
        float lv = l_ws[row] - ldec*DTс;
        l_ws[row] = fminf(1.f, fmaxf(0.f, lv));
    }
}

// ================= finalize: mask + pack outputs =================
__global__ __launch_bounds__(256) void finalize_kernel(
    const float* __restrict__ e_ws, const float* __restrict__ E_ws, const float* __restrict__ P_ws,
    const float* __restrict__ G_ws, const float* __restrict__ m_ws, const float* __restrict__ c,
    const float* __restrict__ l_ws, float* __restrict__ out)
{
    const int srow = blockIdx.x;
    const int tid = threadIdx.x;
    const float lv = l_ws[srow];
    const float af = (lv > 0.05f) ? 1.f : 0.f;
    out[(size_t)srow*DE + tid] = e_ws[(size_t)srow*DE + tid] * af;
    if (tid < DM) {
        out[OFF_M + (size_t)srow*DM + tid] = m_ws[(size_t)srow*DM + tid] * af;
        out[OFF_C + (size_t)srow*DM + tid] = c[(size_t)srow*DM + tid] * af;
    }
    if (tid == 0) {
        out[OFF_E + srow] = E_ws[srow] * af;
        out[OFF_P + srow] = P_ws[srow] * af;
        out[OFF_G + srow] = G_ws[srow] * af;
        out[OFF_L + srow] = lv * af;
        out[OFF_ALIVE + srow] = af;
    }
}

__global__ __launch_bounds__(256) void count_kernel(const float* __restrict__ l_ws, float* __restrict__ out)
{
    __shared__ float sdata[4];
    const int tid = threadIdx.x;
    int cnt = 0;
    for (int i = tid; i < SS; i += 256) cnt += (l_ws[i] > 0.05f) ? 1 : 0;
    float f = (float)cnt;
    #pragma unroll
    for (int mask = 1; mask < 64; mask <<= 1) f += __shfl_xor(f, mask, 64);
    if ((tid & 63) == 0) sdata[tid >> 6] = f;
    __syncthreads();
    if (tid == 0) out[OFF_DIED] = (float)SS - (sdata[0]+sdata[1]+sdata[2]+sdata[3]);
}

extern "C" void kernel_launch(void* const* d_in, const int* in_sizes, int n_in,
                              void* d_out, int out_size, void* d_ws, size_t ws_size,
                              hipStream_t stream) {
    const float* e_in = (const float*)d_in[0];
    const float* E_in = (const float*)d_in[1];
    const float* P_in = (const float*)d_in[2];
    const float* G_in = (const float*)d_in[3];
    const float* m_in = (const float*)d_in[4];
    const float* c_in = (const float*)d_in[5];
    const float* l_in = (const float*)d_in[6];
    const float* wq = (const float*)d_in[7];
    const float* bq = (const float*)d_in[8];
    const float* wk = (const float*)d_in[9];
    const float* bk = (const float*)d_in[10];
    const float* wv = (const float*)d_in[11];
    const float* bv = (const float*)d_in[12];
    const float* alpha = (const float*)d_in[13];
    const float* beta  = (const float*)d_in[14];
    const float* gamma_ = (const float*)d_in[15];
    const float* basal = (const float*)d_in[16];
    float* out = (float*)d_out;
    float* ws = (float*)d_ws;

    float* e_ws = ws + WS_E;
    float* q    = ws + WS_Q;
    float* k    = ws + WS_K;
    float* v    = ws + WS_V;
    float* m_ws = ws + WS_M;
    float* E_ws = ws + WS_EE;
    float* P_ws = ws + WS_PP;
    float* G_ws = ws + WS_GG;
    float* l_ws = ws + WS_LL;
    float* S_in = ws + WS_SIN;
    float* part_m = ws + WS_PM;
    float* part_l = ws + WS_PL;
    float* part_o = ws + WS_PO;

    hipMemcpyAsync(e_ws, e_in, (size_t)SS*DE*sizeof(float), hipMemcpyDeviceToDevice, stream);
    hipMemcpyAsync(m_ws, m_in, (size_t)SS*DM*sizeof(float), hipMemcpyDeviceToDevice, stream);
    hipMemcpyAsync(E_ws, E_in, (size_t)SS*sizeof(float), hipMemcpyDeviceToDevice, stream);
    hipMemcpyAsync(P_ws, P_in, (size_t)SS*sizeof(float), hipMemcpyDeviceToDevice, stream);
    hipMemcpyAsync(G_ws, G_in, (size_t)SS*sizeof(float), hipMemcpyDeviceToDevice, stream);
    hipMemcpyAsync(l_ws, l_in, (size_t)SS*sizeof(float), hipMemcpyDeviceToDevice, stream);

    for (int layer = 0; layer < DEPTH; ++layer) {
        proj_kernel<<<dim3(SS/64, DE/64, 3), 256, 0, stream>>>(
            e_ws, c_in, wq, wk, wv, bq, bk, bv, q, k, v, layer);
        attn_kernel<<<dim3(SS/BQ, KSPLIT), 256, 0, stream>>>(
            q, k, v, m_ws, l_ws, part_o, part_m, part_l);
        combine_kernel<<<dim3(SS/4), 256, 0, stream>>>(
            part_o, part_m, part_l, e_ws, S_in);
        ode_kernel<<<dim3(SS/4), 256, 0, stream>>>(
            S_in, E_ws, P_ws, G_ws, m_ws, l_ws, alpha, beta, gamma_, basal, layer);
    }
    finalize_kernel<<<dim3(SS), 256, 0, stream>>>(
        e_ws, E_ws, P_ws, G_ws, m_ws, c_in, l_ws, out);
    count_kernel<<<1, 256, 0, stream>>>(l_ws, out);
}

// Round 2
// 500.977 us; speedup vs baseline: 8.3825x; 8.3825x over previous
//
#include <hip/hip_runtime.h>
#include <hip/hip_bf16.h>
#include <math.h>

#define SS 4096
#define DE 256
#define DM 64
#define DC 64
#define DIN 320
#define DEPTH 4
#define DT_C 0.1f
#define KSPLIT 8
#define BK 32
#define EXP_SHIFT 8.0f

typedef float f32x4_t __attribute__((ext_vector_type(4)));
typedef __bf16 bf16x8_t __attribute__((ext_vector_type(8)));

#define MFMA_BF16(A, B, C) __builtin_amdgcn_mfma_f32_16x16x32_bf16((A), (B), (C), 0, 0, 0)

// ---------------- output offsets (floats) ----------------
#define OFF_E     (SS*DE)
#define OFF_P     (OFF_E + SS)
#define OFF_G     (OFF_P + SS)
#define OFF_M     (OFF_G + SS)
#define OFF_C     (OFF_M + SS*DM)
#define OFF_L     (OFF_C + SS*DM)
#define OFF_ALIVE (OFF_L + SS)
#define OFF_DIED  (OFF_ALIVE + SS)

// ---------------- ws offsets (float units) ----------------
#define WS_EWS   0                        // SS*DE fp32
#define WS_MWS   (WS_EWS  + SS*DE)        // SS*DM fp32
#define WS_EE    (WS_MWS  + SS*DM)        // SS
#define WS_PP    (WS_EE   + SS)
#define WS_GG    (WS_PP   + SS)
#define WS_LL    (WS_GG   + SS)
#define WS_SIN   (WS_LL   + SS)
#define WS_LSUM  (WS_SIN  + SS)
#define WS_OACC  (WS_LSUM + SS)           // SS*DE fp32
#define WS_XB    (WS_OACC + SS*DE)        // SS*DIN bf16 -> SS*DIN/2 floats
#define WS_QB    (WS_XB  + SS*DIN/2)      // SS*DE bf16
#define WS_KB    (WS_QB  + SS*DE/2)
#define WS_VTB   (WS_KB  + SS*DE/2)       // DE*SS bf16 (transposed V)
#define WS_MB    (WS_VTB + SS*DE/2)       // SS*DM bf16
#define WS_WT    (WS_MB  + SS*DM/2)       // 3*DEPTH*DE*DIN bf16

// LDS strides (bf16 units; all byte strides are multiples of 16)
#define KT_STR 264
#define VT_STR 56
#define MT_STR 72
#define PT_STR 40

// ============== weight transpose: W[z][d][k][n] -> wt[z][d][n][k] bf16 ==============
__global__ __launch_bounds__(256) void transpose_w_kernel(
    const float* __restrict__ wq, const float* __restrict__ wk, const float* __restrict__ wv,
    __hip_bfloat16* __restrict__ wt)
{
    const int zd = blockIdx.z;           // z*DEPTH + d, z = zd>>2
    const int z = zd >> 2;
    const float* src = (z == 0 ? wq : (z == 1 ? wk : wv)) + (size_t)(zd & 3) * DIN * DE;
    __shared__ float t[32][33];
    const int k0 = blockIdx.x * 32;      // DIN/32 = 10
    const int n0 = blockIdx.y * 32;      // DE/32  = 8
    const int tr = threadIdx.x >> 5;     // 0..7
    const int tc = threadIdx.x & 31;
    #pragma unroll
    for (int p = 0; p < 4; ++p)
        t[p*8 + tr][tc] = src[(size_t)(k0 + p*8 + tr) * DE + n0 + tc];
    __syncthreads();
    #pragma unroll
    for (int p = 0; p < 4; ++p) {
        int n = n0 + p*8 + tr;
        int k = k0 + tc;
        wt[((size_t)zd * DE + n) * DIN + k] = __float2bfloat16(t[tc][p*8 + tr]);
    }
}

// ============== m: copy fp32 + cast bf16 ==============
__global__ __launch_bounds__(256) void cast_m_kernel(
    const float* __restrict__ m_in, float* __restrict__ m_ws, __hip_bfloat16* __restrict__ mb)
{
    const int idx = blockIdx.x * 256 + threadIdx.x;   // grid 1024 -> SS*DM
    const float v = m_in[idx];
    m_ws[idx] = v;
    mb[idx] = __float2bfloat16(v);
}

// ============== x = bf16([e | c]) ==============
__global__ __launch_bounds__(256) void build_x_kernel(
    const float* __restrict__ e_ws, const float* __restrict__ c, __hip_bfloat16* __restrict__ xb)
{
    const int idx = blockIdx.x * 256 + threadIdx.x;   // grid 1280 -> SS*80
    const int row = idx / 80, q = idx % 80;
    float4 v;
    if (q < 64) v = *(const float4*)&e_ws[(size_t)row * DE + q * 4];
    else        v = *(const float4*)&c[(size_t)row * DC + (q - 64) * 4];
    __hip_bfloat16 o[4] = {__float2bfloat16(v.x), __float2bfloat16(v.y),
                           __float2bfloat16(v.z), __float2bfloat16(v.w)};
    *(uint2*)&xb[(size_t)row * DIN + q * 4] = *(uint2*)o;
}

// ============== zero O_acc / Lsum ==============
__global__ __launch_bounds__(256) void zero_kernel(float* __restrict__ O_acc, float* __restrict__ Lsum)
{
    const int idx = blockIdx.x * 256 + threadIdx.x;   // grid 1024
    *(float4*)&O_acc[(size_t)idx * 4] = make_float4(0.f, 0.f, 0.f, 0.f);
    if (idx < SS) Lsum[idx] = 0.f;
}

// ============== projections via MFMA: {q,k} row-major bf16, v transposed ==============
__global__ __launch_bounds__(256, 2) void proj_mfma_kernel(
    const __hip_bfloat16* __restrict__ xb, const __hip_bfloat16* __restrict__ wt,
    const float* __restrict__ bq, const float* __restrict__ bk, const float* __restrict__ bv,
    __hip_bfloat16* __restrict__ qb, __hip_bfloat16* __restrict__ kb, __hip_bfloat16* __restrict__ vtb,
    int layer)
{
    const int z = blockIdx.z;
    const int tid = threadIdx.x;
    const int w = tid >> 6, lane = tid & 63;
    const int m = lane & 15, quad = lane >> 4;
    const int row0 = blockIdx.x * 16;
    const __hip_bfloat16* wtz = wt + (size_t)(z * DEPTH + layer) * DE * DIN;
    const float* bias = (z == 0 ? bq : (z == 1 ? bk : bv)) + (size_t)layer * DE;

    bf16x8_t xa[10];
    #pragma unroll
    for (int kk = 0; kk < 10; ++kk)
        xa[kk] = *(const bf16x8_t*)&xb[(size_t)(row0 + m) * DIN + kk * 32 + quad * 8];

    f32x4_t acc[4];
    #pragma unroll
    for (int nt = 0; nt < 4; ++nt) acc[nt] = (f32x4_t){0.f, 0.f, 0.f, 0.f};

    #pragma unroll
    for (int kk = 0; kk < 10; ++kk) {
        #pragma unroll
        for (int nt = 0; nt < 4; ++nt) {
            const int ncol = w * 64 + nt * 16 + m;
            bf16x8_t bfrag = *(const bf16x8_t*)&wtz[(size_t)ncol * DIN + kk * 32 + quad * 8];
            acc[nt] = MFMA_BF16(xa[kk], bfrag, acc[nt]);
        }
    }
    #pragma unroll
    for (int nt = 0; nt < 4; ++nt) {
        const int col = w * 64 + nt * 16 + m;
        const float b = bias[col];
        #pragma unroll
        for (int r = 0; r < 4; ++r) {
            const int row = row0 + quad * 4 + r;
            const __hip_bfloat16 h = __float2bfloat16(acc[nt][r] + b);
            if (z == 0)      qb[(size_t)row * DE + col] = h;
            else if (z == 1) kb[(size_t)row * DE + col] = h;
            else             vtb[(size_t)col * SS + row] = h;
        }
    }
}

// ============== attention: MFMA flash, fixed exp shift, atomic split-combine ==============
__global__ __launch_bounds__(256, 2) void attn_mfma_kernel(
    const __hip_bfloat16* __restrict__ qb, const __hip_bfloat16* __restrict__ kb,
    const __hip_bfloat16* __restrict__ vtb, const __hip_bfloat16* __restrict__ mb,
    const float* __restrict__ l_ws,
    float* __restrict__ O_acc, float* __restrict__ Lsum)
{
    __shared__ __align__(16) __hip_bfloat16 kt[32 * KT_STR];
    __shared__ __align__(16) __hip_bfloat16 vt[256 * VT_STR];
    __shared__ __align__(16) __hip_bfloat16 mt[32 * MT_STR];
    __shared__ __align__(16) __hip_bfloat16 pt[4 * 16 * PT_STR];
    __shared__ float lt[32];

    const int tid = threadIdx.x;
    const int w = tid >> 6, lane = tid & 63;
    const int n = lane & 15, quad = lane >> 4;
    const int row0 = blockIdx.x * 64 + w * 16;
    const int t_begin = blockIdx.y * (SS / KSPLIT);

    bf16x8_t qa[8];
    #pragma unroll
    for (int kk = 0; kk < 8; ++kk)
        qa[kk] = *(const bf16x8_t*)&qb[(size_t)(row0 + n) * DE + kk * 32 + quad * 8];
    bf16x8_t ma[2];
    #pragma unroll
    for (int kk = 0; kk < 2; ++kk)
        ma[kk] = *(const bf16x8_t*)&mb[(size_t)(row0 + n) * DM + kk * 32 + quad * 8];
    float lq[4];
    #pragma unroll
    for (int r = 0; r < 4; ++r) lq[r] = l_ws[row0 + quad * 4 + r] * 0.0625f;  // fold 1/sqrt(DE)

    f32x4_t oacc[16];
    #pragma unroll
    for (int ct = 0; ct < 16; ++ct) oacc[ct] = (f32x4_t){0.f, 0.f, 0.f, 0.f};
    float plsum[4] = {0.f, 0.f, 0.f, 0.f};
    __hip_bfloat16* ptw = &pt[w * 16 * PT_STR];

    for (int t0 = t_begin; t0 < t_begin + SS / KSPLIT; t0 += BK) {
        __syncthreads();
        #pragma unroll
        for (int p = 0; p < 4; ++p) {   // K tile: 32 rows x 256 bf16
            const int idx = tid + p * 256;
            const int row = idx >> 5, g = idx & 31;
            *(float4*)&kt[row * KT_STR + g * 8] = *(const float4*)&kb[(size_t)(t0 + row) * DE + g * 8];
        }
        #pragma unroll
        for (int p = 0; p < 4; ++p) {   // V^T tile: 256 cols x 32 keys
            const int idx = tid + p * 256;
            const int col = idx >> 2, seg = idx & 3;
            *(float4*)&vt[col * VT_STR + seg * 8] = *(const float4*)&vtb[(size_t)col * SS + t0 + seg * 8];
        }
        {                               // M tile: 32 rows x 64 bf16
            const int row = tid >> 3, g = tid & 7;
            *(float4*)&mt[row * MT_STR + g * 8] = *(const float4*)&mb[(size_t)(t0 + row) * DM + g * 8];
        }
        if (tid < 32) lt[tid] = l_ws[t0 + tid];
        __syncthreads();

        f32x4_t sqk0 = (f32x4_t){0.f,0.f,0.f,0.f}, sqk1 = (f32x4_t){0.f,0.f,0.f,0.f};
        f32x4_t smm0 = (f32x4_t){0.f,0.f,0.f,0.f}, smm1 = (f32x4_t){0.f,0.f,0.f,0.f};
        #pragma unroll
        for (int kk = 0; kk < 8; ++kk) {
            bf16x8_t k0 = *(const bf16x8_t*)&kt[n * KT_STR + kk * 32 + quad * 8];
            bf16x8_t k1 = *(const bf16x8_t*)&kt[(n + 16) * KT_STR + kk * 32 + quad * 8];
            sqk0 = MFMA_BF16(qa[kk], k0, sqk0);
            sqk1 = MFMA_BF16(qa[kk], k1, sqk1);
        }
        #pragma unroll
        for (int kk = 0; kk < 2; ++kk) {
            bf16x8_t m0 = *(const bf16x8_t*)&mt[n * MT_STR + kk * 32 + quad * 8];
            bf16x8_t m1 = *(const bf16x8_t*)&mt[(n + 16) * MT_STR + kk * 32 + quad * 8];
            smm0 = MFMA_BF16(ma[kk], m0, smm0);
            smm1 = MFMA_BF16(ma[kk], m1, smm1);
        }
        const float lk0 = lt[n], lk1 = lt[n + 16];
        #pragma unroll
        for (int r = 0; r < 4; ++r) {
            const float x0 = sqk0[r] * lq[r] * lk0 * smm0[r];
            const float x1 = sqk1[r] * lq[r] * lk1 * smm1[r];
            const float p0 = __expf(x0 - EXP_SHIFT);
            const float p1 = __expf(x1 - EXP_SHIFT);
            plsum[r] += p0 + p1;
            ptw[(quad * 4 + r) * PT_STR + n]      = __float2bfloat16(p0);
            ptw[(quad * 4 + r) * PT_STR + 16 + n] = __float2bfloat16(p1);
        }
        const bf16x8_t pa = *(const bf16x8_t*)&ptw[n * PT_STR + quad * 8];
        #pragma unroll
        for (int ct = 0; ct < 16; ++ct) {
            bf16x8_t vb = *(const bf16x8_t*)&vt[(ct * 16 + n) * VT_STR + quad * 8];
            oacc[ct] = MFMA_BF16(pa, vb, oacc[ct]);
        }
    }

    #pragma unroll
    for (int r = 0; r < 4; ++r) {
        float s = plsum[r];
        s += __shfl_xor(s, 1); s += __shfl_xor(s, 2);
        s += __shfl_xor(s, 4); s += __shfl_xor(s, 8);
        plsum[r] = s;
    }
    if (n == 0) {
        #pragma unroll
        for (int r = 0; r < 4; ++r)
            atomicAdd(&Lsum[row0 + quad * 4 + r], plsum[r]);
    }
    #pragma unroll
    for (int ct = 0; ct < 16; ++ct) {
        #pragma unroll
        for (int r = 0; r < 4; ++r)
            atomicAdd(&O_acc[(size_t)(row0 + quad * 4 + r) * DE + ct * 16 + n], oacc[ct][r]);
    }
}

// ============== normalize, e += h, S_in = ||h||^2 ==============
__global__ __launch_bounds__(256) void combine_kernel(
    const float* __restrict__ O_acc, const float* __restrict__ Lsum,
    float* __restrict__ e_ws, float* __restrict__ S_in)
{
    const int w = threadIdx.x >> 6, lane = threadIdx.x & 63;
    const int row = blockIdx.x * 4 + w;
    const float invL = 1.0f / Lsum[row];
    float4 o = *(const float4*)&O_acc[(size_t)row * DE + lane * 4];
    o.x *= invL; o.y *= invL; o.z *= invL; o.w *= invL;
    float4 ev = *(float4*)&e_ws[(size_t)row * DE + lane * 4];
    ev.x += o.x; ev.y += o.y; ev.z += o.z; ev.w += o.w;
    *(float4*)&e_ws[(size_t)row * DE + lane * 4] = ev;
    float ssq = o.x*o.x + o.y*o.y + o.z*o.z + o.w*o.w;
    #pragma unroll
    for (int mask = 1; mask < 64; mask <<= 1) ssq += __shfl_xor(ssq, mask);
    if (lane == 0) S_in[row] = ssq;
}

// ============== thermodynamic ODE ==============
__global__ __launch_bounds__(256) void ode_kernel(
    const float* __restrict__ S_in,
    float* __restrict__ E_ws, float* __restrict__ P_ws, float* __restrict__ G_ws,
    float* __restrict__ m_ws, __hip_bfloat16* __restrict__ mb, float* __restrict__ l_ws,
    const float* __restrict__ alpha, const float* __restrict__ beta,
    const float* __restrict__ gamma_, const float* __restrict__ basal, int layer)
{
    const int w = threadIdx.x >> 6, lane = threadIdx.x & 63;
    const int row = blockIdx.x * 4 + w;
    const float a = alpha[layer], b = beta[layer], gm = gamma_[layer], bas = basal[layer];
    const float E = E_ws[row], P = P_ws[row];
    const float Sin = S_in[row];
    const float PE = P * E;
    const float Pn = fmaxf(0.f, P + (a * Sin - b * PE) * DT_C);
    const float En = fmaxf(0.f, E + (bas - gm * PE) * DT_C);
    const float mtg = 1.f / (1.f + __expf(-(En - Pn)));
    const size_t mi = (size_t)row * DM + lane;
    const float mv = 0.9f * m_ws[mi] + 0.1f * mtg;
    m_ws[mi] = mv;
    mb[mi] = __float2bfloat16(mv);
    if (lane == 0) {
        E_ws[row] = En;
        P_ws[row] = Pn;
        G_ws[row] = G_ws[row] + (0.1f * En - 0.5f * Pn) * DT_C;
        const float ldec = 0.01f + 0.5f * fmaxf(0.f, Pn - 2.0f);
        const float lv = l_ws[row] - ldec * DT_C;
        l_ws[row] = fminf(1.f, fmaxf(0.f, lv));
    }
}

// ============== finalize: mask + pack outputs ==============
__global__ __launch_bounds__(256) void finalize_kernel(
    const float* __restrict__ e_ws, const float* __restrict__ E_ws, const float* __restrict__ P_ws,
    const float* __restrict__ G_ws, const float* __restrict__ m_ws, const float* __restrict__ c,
    const float* __restrict__ l_ws, float* __restrict__ out)
{
    const int srow = blockIdx.x;
    const int tid = threadIdx.x;
    const float lv = l_ws[srow];
    const float af = (lv > 0.05f) ? 1.f : 0.f;
    out[(size_t)srow * DE + tid] = e_ws[(size_t)srow * DE + tid] * af;
    if (tid < DM) {
        out[OFF_M + (size_t)srow * DM + tid] = m_ws[(size_t)srow * DM + tid] * af;
        out[OFF_C + (size_t)srow * DM + tid] = c[(size_t)srow * DM + tid] * af;
    }
    if (tid == 0) {
        out[OFF_E + srow] = E_ws[srow] * af;
        out[OFF_P + srow] = P_ws[srow] * af;
        out[OFF_G + srow] = G_ws[srow] * af;
        out[OFF_L + srow] = lv * af;
        out[OFF_ALIVE + srow] = af;
    }
}

__global__ __launch_bounds__(256) void count_kernel(const float* __restrict__ l_ws, float* __restrict__ out)
{
    __shared__ float sdata[4];
    const int tid = threadIdx.x;
    int cnt = 0;
    for (int i = tid; i < SS; i += 256) cnt += (l_ws[i] > 0.05f) ? 1 : 0;
    float f = (float)cnt;
    #pragma unroll
    for (int mask = 1; mask < 64; mask <<= 1) f += __shfl_xor(f, mask);
    if ((tid & 63) == 0) sdata[tid >> 6] = f;
    __syncthreads();
    if (tid == 0) out[OFF_DIED] = (float)SS - (sdata[0] + sdata[1] + sdata[2] + sdata[3]);
}

extern "C" void kernel_launch(void* const* d_in, const int* in_sizes, int n_in,
                              void* d_out, int out_size, void* d_ws, size_t ws_size,
                              hipStream_t stream) {
    const float* e_in = (const float*)d_in[0];
    const float* E_in = (const float*)d_in[1];
    const float* P_in = (const float*)d_in[2];
    const float* G_in = (const float*)d_in[3];
    const float* m_in = (const float*)d_in[4];
    const float* c_in = (const float*)d_in[5];
    const float* l_in = (const float*)d_in[6];
    const float* wq = (const float*)d_in[7];
    const float* bq = (const float*)d_in[8];
    const float* wk = (const float*)d_in[9];
    const float* bk = (const float*)d_in[10];
    const float* wv = (const float*)d_in[11];
    const float* bv = (const float*)d_in[12];
    const float* alpha = (const float*)d_in[13];
    const float* beta  = (const float*)d_in[14];
    const float* gamma_ = (const float*)d_in[15];
    const float* basal = (const float*)d_in[16];
    float* out = (float*)d_out;
    float* ws = (float*)d_ws;

    float* e_ws = ws + WS_EWS;
    float* m_ws = ws + WS_MWS;
    float* E_ws = ws + WS_EE;
    float* P_ws = ws + WS_PP;
    float* G_ws = ws + WS_GG;
    float* l_ws = ws + WS_LL;
    float* S_in = ws + WS_SIN;
    float* Lsum = ws + WS_LSUM;
    float* O_acc = ws + WS_OACC;
    __hip_bfloat16* xb  = (__hip_bfloat16*)(ws + WS_XB);
    __hip_bfloat16* qb  = (__hip_bfloat16*)(ws + WS_QB);
    __hip_bfloat16* kb  = (__hip_bfloat16*)(ws + WS_KB);
    __hip_bfloat16* vtb = (__hip_bfloat16*)(ws + WS_VTB);
    __hip_bfloat16* mb  = (__hip_bfloat16*)(ws + WS_MB);
    __hip_bfloat16* wt  = (__hip_bfloat16*)(ws + WS_WT);

    hipMemcpyAsync(e_ws, e_in, (size_t)SS*DE*sizeof(float), hipMemcpyDeviceToDevice, stream);
    hipMemcpyAsync(E_ws, E_in, (size_t)SS*sizeof(float), hipMemcpyDeviceToDevice, stream);
    hipMemcpyAsync(P_ws, P_in, (size_t)SS*sizeof(float), hipMemcpyDeviceToDevice, stream);
    hipMemcpyAsync(G_ws, G_in, (size_t)SS*sizeof(float), hipMemcpyDeviceToDevice, stream);
    hipMemcpyAsync(l_ws, l_in, (size_t)SS*sizeof(float), hipMemcpyDeviceToDevice, stream);
    cast_m_kernel<<<dim3(SS*DM/256), 256, 0, stream>>>(m_in, m_ws, mb);
    transpose_w_kernel<<<dim3(DIN/32, DE/32, 12), 256, 0, stream>>>(wq, wk, wv, wt);

    for (int layer = 0; layer < DEPTH; ++layer) {
        zero_kernel<<<dim3(SS*DE/1024), 256, 0, stream>>>(O_acc, Lsum);
        build_x_kernel<<<dim3(SS*80/256), 256, 0, stream>>>(e_ws, c_in, xb);
        proj_mfma_kernel<<<dim3(SS/16, 1, 3), 256, 0, stream>>>(
            xb, wt, bq, bk, bv, qb, kb, vtb, layer);
        attn_mfma_kernel<<<dim3(SS/64, KSPLIT), 256, 0, stream>>>(
            qb, kb, vtb, mb, l_ws, O_acc, Lsum);
        combine_kernel<<<dim3(SS/4), 256, 0, stream>>>(O_acc, Lsum, e_ws, S_in);
        ode_kernel<<<dim3(SS/4), 256, 0, stream>>>(
            S_in, E_ws, P_ws, G_ws, m_ws, mb, l_ws, alpha, beta, gamma_, basal, layer);
    }
    finalize_kernel<<<dim3(SS), 256, 0, stream>>>(
        e_ws, E_ws, P_ws, G_ws, m_ws, c_in, l_ws, out);
    count_kernel<<<1, 256, 0, stream>>>(l_ws, out);
}